// Round 1
// baseline (13898.555 us; speedup 1.0000x reference)
//
#include <hip/hip_runtime.h>
#include <hip/hip_bf16.h>

#define N_NODES 4096
#define T_STEPS 8
#define INDIM   64
#define HDIM    128
#define G4      512                    // 4*H
#define NROWS   (N_NODES * T_STEPS)    // 32768

typedef __hip_bfloat16 bf16;

__device__ __forceinline__ float sigm(float x) { return 1.0f / (1.0f + __expf(-x)); }
__device__ __forceinline__ float tanh_(float x) {
    x = fminf(fmaxf(x, -15.f), 15.f);
    float e = __expf(2.f * x);
    return (e - 1.f) / (e + 1.f);
}

// ---------------- K0: fold weights -------------------------------------------
// Wc[g][i] = sum_k pre_w[i,k]*w_ih[g,k]          (512x64)
// bc[g]    = sum_k pre_b[k]*w_ih[g,k] + b_ih[g] + b_hh[g]
// wsT/wdT  = transposed gat weights (col-major access for fs/fd GEMM)
// wso[hi]  = sum_ho wsrc[hi,ho]*out_w[ho]
// cy       = sum_h gat_b[h]*out_w[h] + out_b
__global__ void prep_kernel(const float* __restrict__ pre_w, const float* __restrict__ pre_b,
                            const float* __restrict__ w_ih, const float* __restrict__ b_ih,
                            const float* __restrict__ b_hh,
                            const float* __restrict__ wsrc, const float* __restrict__ wdst,
                            const float* __restrict__ out_w, const float* __restrict__ out_b,
                            const float* __restrict__ gat_b,
                            float* __restrict__ Wc, float* __restrict__ bc,
                            float* __restrict__ wsT, float* __restrict__ wdT,
                            float* __restrict__ wso, float* __restrict__ cy) {
    int id = blockIdx.x * 256 + threadIdx.x;
    if (id < 32768) {
        int g = id >> 6, i = id & 63;
        float s = 0.f;
        for (int k = 0; k < HDIM; k++) s += pre_w[i * HDIM + k] * w_ih[g * HDIM + k];
        Wc[id] = s;
    } else if (id < 32768 + 512) {
        int g = id - 32768;
        float s = b_ih[g] + b_hh[g];
        for (int k = 0; k < HDIM; k++) s += pre_b[k] * w_ih[g * HDIM + k];
        bc[g] = s;
    } else if (id < 32768 + 512 + 16384) {
        int c = id - (32768 + 512);
        int co = c >> 7, k = c & 127;
        wsT[c] = wsrc[k * HDIM + co];
    } else if (id < 32768 + 512 + 32768) {
        int c = id - (32768 + 512 + 16384);
        int co = c >> 7, k = c & 127;
        wdT[c] = wdst[k * HDIM + co];
    } else if (id < 32768 + 512 + 32768 + 128) {
        int hi = id - (32768 + 512 + 32768);
        float s = 0.f;
        for (int ho = 0; ho < HDIM; ho++) s += wsrc[hi * HDIM + ho] * out_w[ho];
        wso[hi] = s;
    } else if (id == 32768 + 512 + 32768 + 128) {
        float s = out_b[0];
        for (int h = 0; h < HDIM; h++) s += gat_b[h] * out_w[h];
        cy[0] = s;
    }
}

// ---------------- K1: xw[row][g] = input[row,:64] . Wc[g,:] + bc[g] ----------
__global__ __launch_bounds__(512) void xw_kernel(const float* __restrict__ input,
                                                 const float* __restrict__ Wc,
                                                 const float* __restrict__ bc,
                                                 bf16* __restrict__ xw) {
    __shared__ __align__(16) float in_lds[16 * INDIM];   // 4KB: 16 rows
    int tid = threadIdx.x;
    int rowbase = blockIdx.x * 16;
    in_lds[tid]       = input[(size_t)rowbase * INDIM + tid];
    in_lds[tid + 512] = input[(size_t)rowbase * INDIM + tid + 512];
    __syncthreads();
    int g = tid;
    float4 w[16];
    const float4* wr = reinterpret_cast<const float4*>(Wc + g * INDIM);
#pragma unroll
    for (int u = 0; u < 16; u++) w[u] = wr[u];
    float b = bc[g];
    for (int r = 0; r < 16; r++) {
        const float4* hv = reinterpret_cast<const float4*>(in_lds + r * INDIM);
        float a0 = b, a1 = 0.f, a2 = 0.f, a3 = 0.f;
#pragma unroll
        for (int u = 0; u < 16; u++) {
            float4 h4 = hv[u]; float4 wv = w[u];
            a0 = fmaf(h4.x, wv.x, a0); a1 = fmaf(h4.y, wv.y, a1);
            a2 = fmaf(h4.z, wv.z, a2); a3 = fmaf(h4.w, wv.w, a3);
        }
        xw[(size_t)(rowbase + r) * G4 + g] = __float2bfloat16((a0 + a1) + (a2 + a3));
    }
}

// ---------------- K2: sequential LSTM scan over nodes ------------------------
// 8 blocks (one per t-chain), 512 threads; thread g owns w_hh row g in VGPRs.
#define LSTM_SUBSTEP(NIDX, XWREG)                                                   \
    do {                                                                            \
        float a0 = (XWREG), a1 = 0.f, a2 = 0.f, a3 = 0.f;                           \
        _Pragma("unroll")                                                           \
        for (int u = 0; u < 32; u++) {                                              \
            float4 hv = h4[u]; float4 wv = wreg[u];                                 \
            a0 = fmaf(hv.x, wv.x, a0); a1 = fmaf(hv.y, wv.y, a1);                   \
            a2 = fmaf(hv.z, wv.z, a2); a3 = fmaf(hv.w, wv.w, a3);                   \
        }                                                                           \
        g_lds[g] = (a0 + a1) + (a2 + a3);                                           \
        __syncthreads();                                                            \
        if (tid < HDIM) {                                                           \
            float ig = g_lds[tid], fg = g_lds[HDIM + tid];                          \
            float gg = g_lds[2 * HDIM + tid], og = g_lds[3 * HDIM + tid];           \
            cloc = sigm(fg) * cloc + sigm(ig) * tanh_(gg);                          \
            hloc = sigm(og) * tanh_(cloc);                                          \
            outs[(size_t)((NIDX) * T_STEPS + t) * HDIM + tid] = hloc;               \
            h_lds[tid] = hloc;                                                      \
        }                                                                           \
        __syncthreads();                                                            \
    } while (0)

__global__ __launch_bounds__(512) void lstm_kernel(const bf16* __restrict__ xw,
                                                   const float* __restrict__ w_hh,
                                                   const float* __restrict__ hidden0,
                                                   const float* __restrict__ cell0,
                                                   float* __restrict__ outs,
                                                   float* __restrict__ dout) {
    __shared__ __align__(16) float h_lds[HDIM];
    __shared__ __align__(16) float g_lds[G4];
    int tid = threadIdx.x;
    int t = blockIdx.x;
    int g = tid;
    float4 wreg[32];                                   // w_hh[g, 0..127] -> 128 VGPR
    const float4* wr = reinterpret_cast<const float4*>(w_hh + (size_t)g * HDIM);
#pragma unroll
    for (int u = 0; u < 32; u++) wreg[u] = wr[u];
    float hloc = 0.f, cloc = 0.f;
    if (tid < HDIM) {
        h_lds[tid] = hidden0[t * HDIM + tid];
        cloc = cell0[t * HDIM + tid];
    }
    // xw flat index (n*8+t)*512+g = n*4096 + t*512 + g
    const bf16* xp = xw + (size_t)t * G4 + g;
    float xwA = __bfloat162float(xp[0]);
    float xwB = __bfloat162float(xp[4096]);
    __syncthreads();
    const float4* h4 = reinterpret_cast<const float4*>(h_lds);
    for (int n = 0; n < N_NODES; n += 2) {
        float pfA = (n + 2 < N_NODES) ? __bfloat162float(xp[(size_t)(n + 2) * 4096]) : 0.f;
        float pfB = (n + 3 < N_NODES) ? __bfloat162float(xp[(size_t)(n + 3) * 4096]) : 0.f;
        LSTM_SUBSTEP(n, xwA);
        xwA = pfA;
        LSTM_SUBSTEP(n + 1, xwB);
        xwB = pfB;
    }
    if (tid < HDIM) {
        dout[NROWS + t * HDIM + tid] = hloc;                       // hT
        dout[NROWS + T_STEPS * HDIM + t * HDIM + tid] = cloc;      // cT
    }
}

// ---------------- K3: fs = outs@wsrc, fd = outs@wdst (bf16 out) --------------
__global__ __launch_bounds__(256) void fsfd_kernel(const float* __restrict__ outs,
                                                   const float* __restrict__ wsT,
                                                   const float* __restrict__ wdT,
                                                   bf16* __restrict__ fs,
                                                   bf16* __restrict__ fd) {
    __shared__ __align__(16) float rows[32 * HDIM];    // 16KB: 32 rows
    int tid = threadIdx.x;
    size_t base = (size_t)blockIdx.x * 32 * HDIM;
#pragma unroll
    for (int j = 0; j < 16; j++) rows[tid + j * 256] = outs[base + tid + j * 256];
    __syncthreads();
    int c = tid;
    const float4* wT = reinterpret_cast<const float4*>(
        (c < HDIM) ? (wsT + c * HDIM) : (wdT + (c - HDIM) * HDIM));
    float4 w[32];
#pragma unroll
    for (int u = 0; u < 32; u++) w[u] = wT[u];
    bf16* dst = (c < HDIM) ? (fs + base + c) : (fd + base + (c - HDIM));
    for (int r = 0; r < 32; r++) {
        const float4* hv = reinterpret_cast<const float4*>(rows + r * HDIM);
        float a0 = 0.f, a1 = 0.f, a2 = 0.f, a3 = 0.f;
#pragma unroll
        for (int u = 0; u < 32; u++) {
            float4 h4 = hv[u]; float4 wv = w[u];
            a0 = fmaf(h4.x, wv.x, a0); a1 = fmaf(h4.y, wv.y, a1);
            a2 = fmaf(h4.z, wv.z, a2); a3 = fmaf(h4.w, wv.w, a3);
        }
        dst[(size_t)r * HDIM] = __float2bfloat16((a0 + a1) + (a2 + a3));
    }
}

// ---------------- K3b: fso[row] = outs[row,:] . wso --------------------------
__global__ __launch_bounds__(256) void fso_kernel(const float* __restrict__ outs,
                                                  const float* __restrict__ wso,
                                                  float* __restrict__ fso) {
    int tid = threadIdx.x;
    int l = tid & 63;
    int row = blockIdx.x * 4 + (tid >> 6);
    float v = outs[(size_t)row * HDIM + l] * wso[l]
            + outs[(size_t)row * HDIM + 64 + l] * wso[64 + l];
#pragma unroll
    for (int m = 32; m >= 1; m >>= 1) v += __shfl_xor(v, m, 64);
    if (l == 0) fso[row] = v;
}

// ---------------- K4: per-edge softmax numerators ----------------------------
// y[n,t] = (sum_e a*fso[src,t]) / (sum_e a) + cy ; a = exp(leaky(fs_s+fd_d).attn)
__global__ __launch_bounds__(256) void edge_kernel(const int* __restrict__ esrc,
                                                   const int* __restrict__ edst,
                                                   const bf16* __restrict__ fs,
                                                   const bf16* __restrict__ fd,
                                                   const float* __restrict__ attn,
                                                   const float* __restrict__ fso,
                                                   float* __restrict__ denom,
                                                   float* __restrict__ ynum, int nE) {
    int tid = threadIdx.x;
    int l = tid & 63;
    int e = blockIdx.x * 4 + (tid >> 6);
    if (e >= nE) return;
    int s = esrc[e], d = edst[e];
    float at1 = attn[l], at2 = attn[64 + l];
    const bf16* fsr = fs + (size_t)s * (T_STEPS * HDIM);
    const bf16* fdr = fd + (size_t)d * (T_STEPS * HDIM);
#pragma unroll
    for (int t = 0; t < T_STEPS; t++) {
        float x1 = __bfloat162float(fsr[t * HDIM + l]) + __bfloat162float(fdr[t * HDIM + l]);
        float x2 = __bfloat162float(fsr[t * HDIM + 64 + l]) + __bfloat162float(fdr[t * HDIM + 64 + l]);
        x1 = fmaxf(x1, 0.f) + 0.2f * fminf(x1, 0.f);
        x2 = fmaxf(x2, 0.f) + 0.2f * fminf(x2, 0.f);
        float v = x1 * at1 + x2 * at2;
#pragma unroll
        for (int m = 32; m >= 1; m >>= 1) v += __shfl_xor(v, m, 64);
        if (l == 0) {
            float a = __expf(v);
            atomicAdd(&denom[d * T_STEPS + t], a);
            atomicAdd(&ynum[d * T_STEPS + t], a * fso[s * T_STEPS + t]);
        }
    }
}

// ---------------- K5: finalize y ---------------------------------------------
__global__ void final_kernel(const float* __restrict__ ynum, const float* __restrict__ denom,
                             const float* __restrict__ cy, float* __restrict__ dout) {
    int i = blockIdx.x * 256 + threadIdx.x;
    if (i < NROWS) dout[i] = ynum[i] / denom[i] + cy[0];
}

extern "C" void kernel_launch(void* const* d_in, const int* in_sizes, int n_in,
                              void* d_out, int out_size, void* d_ws, size_t ws_size,
                              hipStream_t stream) {
    const float* input  = (const float*)d_in[0];
    const float* hidden = (const float*)d_in[1];
    const float* cell   = (const float*)d_in[2];
    const float* pre_w  = (const float*)d_in[3];
    const float* pre_b  = (const float*)d_in[4];
    const float* w_ih   = (const float*)d_in[5];
    const float* w_hh   = (const float*)d_in[6];
    const float* b_ih   = (const float*)d_in[7];
    const float* b_hh   = (const float*)d_in[8];
    const float* wsrc   = (const float*)d_in[9];
    const float* wdst   = (const float*)d_in[10];
    const float* attn   = (const float*)d_in[11];
    const float* gatb   = (const float*)d_in[12];
    const float* outw   = (const float*)d_in[13];
    const float* outb   = (const float*)d_in[14];
    const int*   esrc   = (const int*)d_in[15];
    const int*   edst   = (const int*)d_in[16];
    int nE = in_sizes[15];
    float* dout = (float*)d_out;
    char* ws = (char*)d_ws;

    // workspace layout (bytes, 256-aligned)
    const size_t o_xw    = 0;                 // 32768*512*2  = 33,554,432
    const size_t o_outs  = 33554432;          // 32768*128*4  = 16,777,216
    const size_t o_fs    = 50331648;          // 32768*128*2  =  8,388,608
    const size_t o_fd    = 58720256;          //               8,388,608
    const size_t o_fso   = 67108864;          // 32768*4      =    131,072
    const size_t o_denom = 67239936;          //    131,072
    const size_t o_ynum  = 67371008;          //    131,072   (adjacent to denom)
    const size_t o_wc    = 67502080;          //    131,072
    const size_t o_bc    = 67633152;          //      2,048
    const size_t o_wsT   = 67635200;          //     65,536
    const size_t o_wdT   = 67700736;          //     65,536
    const size_t o_wso   = 67766272;          //        512
    const size_t o_cy    = 67766784;          //          4

    bf16*  xw    = (bf16*)(ws + o_xw);
    float* outs  = (float*)(ws + o_outs);
    bf16*  fs    = (bf16*)(ws + o_fs);
    bf16*  fd    = (bf16*)(ws + o_fd);
    float* fso   = (float*)(ws + o_fso);
    float* denom = (float*)(ws + o_denom);
    float* ynum  = (float*)(ws + o_ynum);
    float* Wc    = (float*)(ws + o_wc);
    float* bc    = (float*)(ws + o_bc);
    float* wsT   = (float*)(ws + o_wsT);
    float* wdT   = (float*)(ws + o_wdT);
    float* wso   = (float*)(ws + o_wso);
    float* cy    = (float*)(ws + o_cy);

    prep_kernel<<<259, 256, 0, stream>>>(pre_w, pre_b, w_ih, b_ih, b_hh, wsrc, wdst,
                                         outw, outb, gatb, Wc, bc, wsT, wdT, wso, cy);
    xw_kernel<<<2048, 512, 0, stream>>>(input, Wc, bc, xw);
    lstm_kernel<<<8, 512, 0, stream>>>(xw, w_hh, hidden, cell, outs, dout);
    fsfd_kernel<<<1024, 256, 0, stream>>>(outs, wsT, wdT, fs, fd);
    fso_kernel<<<8192, 256, 0, stream>>>(outs, wso, fso);
    hipMemsetAsync(ws + o_denom, 0, 262144, stream);   // denom + ynum
    edge_kernel<<<(nE + 3) / 4, 256, 0, stream>>>(esrc, edst, fs, fd, attn, fso,
                                                  denom, ynum, nE);
    final_kernel<<<128, 256, 0, stream>>>(ynum, denom, cy, dout);
}

// Round 2
// 4223.634 us; speedup vs baseline: 3.2907x; 3.2907x over previous
//
#include <hip/hip_runtime.h>
#include <hip/hip_bf16.h>

#define N_NODES 4096
#define T_STEPS 8
#define INDIM   64
#define HDIM    128
#define G4      512                    // 4*H
#define NROWS   (N_NODES * T_STEPS)    // 32768

typedef __hip_bfloat16 bf16;
typedef __attribute__((ext_vector_type(8))) short bf16x8;
typedef __attribute__((ext_vector_type(4))) float f32x4;

__device__ __forceinline__ float sigm(float x) { return 1.0f / (1.0f + __expf(-x)); }
__device__ __forceinline__ float tanh_(float x) {
    x = fminf(fmaxf(x, -15.f), 15.f);
    float e = __expf(2.f * x);
    return (e - 1.f) / (e + 1.f);
}
__device__ __forceinline__ float bfbits2f(unsigned short u) {
    union { unsigned int i; float f; } v; v.i = ((unsigned int)u) << 16; return v.f;
}

// ---------------- K0: fold weights + bf16 conversions ------------------------
// Wc[g][i] = sum_k pre_w[i,k]*w_ih[g,k]          (512x64)
// bc[g]    = sum_k pre_b[k]*w_ih[g,k] + b_ih[g] + b_hh[g]
// wsT/wdT  = transposed gat weights; wso = wsrc@out_w; cy = gat_b.out_w+out_b
// whhb     = bf16(w_hh)  (512x128)
#define P_O0 32768
#define P_O1 (P_O0 + 512)
#define P_O2 (P_O1 + 16384)
#define P_O3 (P_O2 + 16384)
#define P_O4 (P_O3 + 128)
#define P_O5 (P_O4 + 1)
#define P_O6 (P_O5 + 65536)
__global__ void prep_kernel(const float* __restrict__ pre_w, const float* __restrict__ pre_b,
                            const float* __restrict__ w_ih, const float* __restrict__ b_ih,
                            const float* __restrict__ b_hh, const float* __restrict__ w_hh,
                            const float* __restrict__ wsrc, const float* __restrict__ wdst,
                            const float* __restrict__ out_w, const float* __restrict__ out_b,
                            const float* __restrict__ gat_b,
                            float* __restrict__ Wc, float* __restrict__ bc,
                            float* __restrict__ wsT, float* __restrict__ wdT,
                            float* __restrict__ wso, float* __restrict__ cy,
                            bf16* __restrict__ whhb) {
    int id = blockIdx.x * 256 + threadIdx.x;
    if (id < P_O0) {
        int g = id >> 6, i = id & 63;
        float s = 0.f;
        for (int k = 0; k < HDIM; k++) s += pre_w[i * HDIM + k] * w_ih[g * HDIM + k];
        Wc[id] = s;
    } else if (id < P_O1) {
        int g = id - P_O0;
        float s = b_ih[g] + b_hh[g];
        for (int k = 0; k < HDIM; k++) s += pre_b[k] * w_ih[g * HDIM + k];
        bc[g] = s;
    } else if (id < P_O2) {
        int c = id - P_O1;
        int co = c >> 7, k = c & 127;
        wsT[c] = wsrc[k * HDIM + co];
    } else if (id < P_O3) {
        int c = id - P_O2;
        int co = c >> 7, k = c & 127;
        wdT[c] = wdst[k * HDIM + co];
    } else if (id < P_O4) {
        int hi = id - P_O3;
        float s = 0.f;
        for (int ho = 0; ho < HDIM; ho++) s += wsrc[hi * HDIM + ho] * out_w[ho];
        wso[hi] = s;
    } else if (id == P_O4) {
        float s = out_b[0];
        for (int h = 0; h < HDIM; h++) s += gat_b[h] * out_w[h];
        cy[0] = s;
    } else if (id < P_O6) {
        int c = id - P_O5;
        whhb[c] = __float2bfloat16(w_hh[c]);
    }
}

// ---------------- K1: xw[row][g] = input[row,:64] . Wc[g,:] + bc[g] ----------
__global__ __launch_bounds__(512) void xw_kernel(const float* __restrict__ input,
                                                 const float* __restrict__ Wc,
                                                 const float* __restrict__ bc,
                                                 bf16* __restrict__ xw) {
    __shared__ __align__(16) float in_lds[16 * INDIM];   // 4KB: 16 rows
    int tid = threadIdx.x;
    int rowbase = blockIdx.x * 16;
    in_lds[tid]       = input[(size_t)rowbase * INDIM + tid];
    in_lds[tid + 512] = input[(size_t)rowbase * INDIM + tid + 512];
    __syncthreads();
    int g = tid;
    float4 w[16];
    const float4* wr = reinterpret_cast<const float4*>(Wc + g * INDIM);
#pragma unroll
    for (int u = 0; u < 16; u++) w[u] = wr[u];
    float b = bc[g];
    for (int r = 0; r < 16; r++) {
        const float4* hv = reinterpret_cast<const float4*>(in_lds + r * INDIM);
        float a0 = b, a1 = 0.f, a2 = 0.f, a3 = 0.f;
#pragma unroll
        for (int u = 0; u < 16; u++) {
            float4 h4 = hv[u]; float4 wv = w[u];
            a0 = fmaf(h4.x, wv.x, a0); a1 = fmaf(h4.y, wv.y, a1);
            a2 = fmaf(h4.z, wv.z, a2); a3 = fmaf(h4.w, wv.w, a3);
        }
        xw[(size_t)(rowbase + r) * G4 + g] = __float2bfloat16((a0 + a1) + (a2 + a3));
    }
}

// ---------------- K2: sequential LSTM scan via MFMA --------------------------
// 8 blocks (one per t-chain), 256 threads (4 waves).
// Wave w holds A-fragments of w_hh rows [w*128, w*128+128) in VGPRs:
//   8 M-tiles x 4 K-tiles of mfma_f32_16x16x32_bf16.
// Per step: B-frag broadcast of h (bf16, LDS), 32 MFMA, C->LDS (lanes l%16==0),
// barrier, gate math on threads 0..127 (xw prefetched 2 steps ahead), barrier.
__global__ __launch_bounds__(256) void lstm_kernel(const bf16* __restrict__ xw,
                                                   const bf16* __restrict__ whhb,
                                                   const float* __restrict__ hidden0,
                                                   const float* __restrict__ cell0,
                                                   float* __restrict__ outs,
                                                   float* __restrict__ dout) {
    __shared__ __align__(16) bf16  h_bf[HDIM];     // 256 B
    __shared__ __align__(16) float g_lds[G4];      // 2 KB
    const int tid  = threadIdx.x;
    const int t    = blockIdx.x;
    const int w    = tid >> 6;
    const int lane = tid & 63;
    const int lr   = lane & 15;        // row-within-tile (A/C row index)
    const int kg   = lane >> 4;        // k-group 0..3

    // Load persistent A fragments: A[r][k] = whhb[(w*128 + mt*16 + lr)*128 + kt*32 + kg*8 + j]
    bf16x8 afr[8][4];
#pragma unroll
    for (int mt = 0; mt < 8; mt++) {
        const unsigned short* rowp =
            reinterpret_cast<const unsigned short*>(whhb) + (size_t)(w * 128 + mt * 16 + lr) * HDIM;
#pragma unroll
        for (int kt = 0; kt < 4; kt++)
            afr[mt][kt] = *reinterpret_cast<const bf16x8*>(rowp + kt * 32 + kg * 8);
    }

    float cloc = 0.f, hloc = 0.f;
    if (tid < HDIM) {
        float h0 = hidden0[t * HDIM + tid];
        h_bf[tid] = __float2bfloat16(h0);
        cloc = cell0[t * HDIM + tid];
    }
    // xw prefetch (gate threads only): rows {tid, 128+tid, 256+tid, 384+tid}
    const unsigned short* xq = reinterpret_cast<const unsigned short*>(xw) + (size_t)t * G4 + tid;
    unsigned short xA[4] = {0, 0, 0, 0}, xB[4] = {0, 0, 0, 0};
    if (tid < HDIM) {
#pragma unroll
        for (int j = 0; j < 4; j++) { xA[j] = xq[j * 128]; xB[j] = xq[4096 + j * 128]; }
    }
    __syncthreads();

    for (int n = 0; n < N_NODES; n++) {
        // B fragment: broadcast h; lane reads h_bf[kt*32 + kg*8 .. +8]
        bf16x8 bfr[4];
#pragma unroll
        for (int kt = 0; kt < 4; kt++)
            bfr[kt] = *reinterpret_cast<const bf16x8*>(&h_bf[kt * 32 + kg * 8]);

        f32x4 acc[8];
#pragma unroll
        for (int mt = 0; mt < 8; mt++) {
            f32x4 a = {0.f, 0.f, 0.f, 0.f};
#pragma unroll
            for (int kt = 0; kt < 4; kt++)
                a = __builtin_amdgcn_mfma_f32_16x16x32_bf16(afr[mt][kt], bfr[kt], a, 0, 0, 0);
            acc[mt] = a;
        }
        // C layout: col=lane&15 (dummy), row=(lane>>4)*4+reg. Col 0 lanes write gates.
        if (lr == 0) {
#pragma unroll
            for (int mt = 0; mt < 8; mt++)
                *reinterpret_cast<f32x4*>(&g_lds[w * 128 + mt * 16 + kg * 4]) = acc[mt];
        }
        __syncthreads();
        if (tid < HDIM) {
            float ig = g_lds[tid]           + bfbits2f(xA[0]);
            float fg = g_lds[HDIM + tid]    + bfbits2f(xA[1]);
            float gg = g_lds[2 * HDIM + tid] + bfbits2f(xA[2]);
            float og = g_lds[3 * HDIM + tid] + bfbits2f(xA[3]);
            cloc = sigm(fg) * cloc + sigm(ig) * tanh_(gg);
            hloc = sigm(og) * tanh_(cloc);
            outs[(size_t)(n * T_STEPS + t) * HDIM + tid] = hloc;
            h_bf[tid] = __float2bfloat16(hloc);
            // rotate prefetch: xA <- xB, load n+2
#pragma unroll
            for (int j = 0; j < 4; j++) xA[j] = xB[j];
            int n2 = n + 2;
            if (n2 < N_NODES) {
#pragma unroll
                for (int j = 0; j < 4; j++) xB[j] = xq[(size_t)n2 * 4096 + j * 128];
            }
        }
        __syncthreads();
    }
    if (tid < HDIM) {
        dout[NROWS + t * HDIM + tid] = hloc;                       // hT
        dout[NROWS + T_STEPS * HDIM + t * HDIM + tid] = cloc;      // cT
    }
}

// ---------------- K3: fs = outs@wsrc, fd = outs@wdst (bf16 out) --------------
__global__ __launch_bounds__(256) void fsfd_kernel(const float* __restrict__ outs,
                                                   const float* __restrict__ wsT,
                                                   const float* __restrict__ wdT,
                                                   bf16* __restrict__ fs,
                                                   bf16* __restrict__ fd) {
    __shared__ __align__(16) float rows[32 * HDIM];    // 16KB: 32 rows
    int tid = threadIdx.x;
    size_t base = (size_t)blockIdx.x * 32 * HDIM;
#pragma unroll
    for (int j = 0; j < 16; j++) rows[tid + j * 256] = outs[base + tid + j * 256];
    __syncthreads();
    int c = tid;
    const float4* wT = reinterpret_cast<const float4*>(
        (c < HDIM) ? (wsT + c * HDIM) : (wdT + (c - HDIM) * HDIM));
    float4 w[32];
#pragma unroll
    for (int u = 0; u < 32; u++) w[u] = wT[u];
    bf16* dst = (c < HDIM) ? (fs + base + c) : (fd + base + (c - HDIM));
    for (int r = 0; r < 32; r++) {
        const float4* hv = reinterpret_cast<const float4*>(rows + r * HDIM);
        float a0 = 0.f, a1 = 0.f, a2 = 0.f, a3 = 0.f;
#pragma unroll
        for (int u = 0; u < 32; u++) {
            float4 h4 = hv[u]; float4 wv = w[u];
            a0 = fmaf(h4.x, wv.x, a0); a1 = fmaf(h4.y, wv.y, a1);
            a2 = fmaf(h4.z, wv.z, a2); a3 = fmaf(h4.w, wv.w, a3);
        }
        dst[(size_t)r * HDIM] = __float2bfloat16((a0 + a1) + (a2 + a3));
    }
}

// ---------------- K3b: fso[row] = outs[row,:] . wso --------------------------
__global__ __launch_bounds__(256) void fso_kernel(const float* __restrict__ outs,
                                                  const float* __restrict__ wso,
                                                  float* __restrict__ fso) {
    int tid = threadIdx.x;
    int l = tid & 63;
    int row = blockIdx.x * 4 + (tid >> 6);
    float v = outs[(size_t)row * HDIM + l] * wso[l]
            + outs[(size_t)row * HDIM + 64 + l] * wso[64 + l];
#pragma unroll
    for (int m = 32; m >= 1; m >>= 1) v += __shfl_xor(v, m, 64);
    if (l == 0) fso[row] = v;
}

// ---------------- K4: per-edge softmax numerators ----------------------------
__global__ __launch_bounds__(256) void edge_kernel(const int* __restrict__ esrc,
                                                   const int* __restrict__ edst,
                                                   const bf16* __restrict__ fs,
                                                   const bf16* __restrict__ fd,
                                                   const float* __restrict__ attn,
                                                   const float* __restrict__ fso,
                                                   float* __restrict__ denom,
                                                   float* __restrict__ ynum, int nE) {
    int tid = threadIdx.x;
    int l = tid & 63;
    int e = blockIdx.x * 4 + (tid >> 6);
    if (e >= nE) return;
    int s = esrc[e], d = edst[e];
    float at1 = attn[l], at2 = attn[64 + l];
    const bf16* fsr = fs + (size_t)s * (T_STEPS * HDIM);
    const bf16* fdr = fd + (size_t)d * (T_STEPS * HDIM);
#pragma unroll
    for (int t = 0; t < T_STEPS; t++) {
        float x1 = __bfloat162float(fsr[t * HDIM + l]) + __bfloat162float(fdr[t * HDIM + l]);
        float x2 = __bfloat162float(fsr[t * HDIM + 64 + l]) + __bfloat162float(fdr[t * HDIM + 64 + l]);
        x1 = fmaxf(x1, 0.f) + 0.2f * fminf(x1, 0.f);
        x2 = fmaxf(x2, 0.f) + 0.2f * fminf(x2, 0.f);
        float v = x1 * at1 + x2 * at2;
#pragma unroll
        for (int m = 32; m >= 1; m >>= 1) v += __shfl_xor(v, m, 64);
        if (l == 0) {
            float a = __expf(v);
            atomicAdd(&denom[d * T_STEPS + t], a);
            atomicAdd(&ynum[d * T_STEPS + t], a * fso[s * T_STEPS + t]);
        }
    }
}

// ---------------- K5: finalize y ---------------------------------------------
__global__ void final_kernel(const float* __restrict__ ynum, const float* __restrict__ denom,
                             const float* __restrict__ cy, float* __restrict__ dout) {
    int i = blockIdx.x * 256 + threadIdx.x;
    if (i < NROWS) dout[i] = ynum[i] / denom[i] + cy[0];
}

extern "C" void kernel_launch(void* const* d_in, const int* in_sizes, int n_in,
                              void* d_out, int out_size, void* d_ws, size_t ws_size,
                              hipStream_t stream) {
    const float* input  = (const float*)d_in[0];
    const float* hidden = (const float*)d_in[1];
    const float* cell   = (const float*)d_in[2];
    const float* pre_w  = (const float*)d_in[3];
    const float* pre_b  = (const float*)d_in[4];
    const float* w_ih   = (const float*)d_in[5];
    const float* w_hh   = (const float*)d_in[6];
    const float* b_ih   = (const float*)d_in[7];
    const float* b_hh   = (const float*)d_in[8];
    const float* wsrc   = (const float*)d_in[9];
    const float* wdst   = (const float*)d_in[10];
    const float* attn   = (const float*)d_in[11];
    const float* gatb   = (const float*)d_in[12];
    const float* outw   = (const float*)d_in[13];
    const float* outb   = (const float*)d_in[14];
    const int*   esrc   = (const int*)d_in[15];
    const int*   edst   = (const int*)d_in[16];
    int nE = in_sizes[15];
    float* dout = (float*)d_out;
    char* ws = (char*)d_ws;

    // workspace layout (bytes, 256-aligned)
    const size_t o_xw    = 0;                 // 32768*512*2  = 33,554,432
    const size_t o_outs  = 33554432;          // 32768*128*4  = 16,777,216
    const size_t o_fs    = 50331648;          // 32768*128*2  =  8,388,608
    const size_t o_fd    = 58720256;          //               8,388,608
    const size_t o_fso   = 67108864;          // 32768*4      =    131,072
    const size_t o_denom = 67239936;          //    131,072
    const size_t o_ynum  = 67371008;          //    131,072
    const size_t o_wc    = 67502080;          //    131,072
    const size_t o_bc    = 67633152;          //      2,048
    const size_t o_wsT   = 67635200;          //     65,536
    const size_t o_wdT   = 67700736;          //     65,536
    const size_t o_wso   = 67766272;          //        512
    const size_t o_cy    = 67766784;          //          4
    // whhb (bf16 w_hh, 128 KiB) OVERLAPS fs: whhb is only read during lstm,
    // fs is only written afterwards (fsfd) — disjoint in time, zero new footprint.
    const size_t o_whhb  = o_fs;

    bf16*  xw    = (bf16*)(ws + o_xw);
    float* outs  = (float*)(ws + o_outs);
    bf16*  fs    = (bf16*)(ws + o_fs);
    bf16*  fd    = (bf16*)(ws + o_fd);
    float* fso   = (float*)(ws + o_fso);
    float* denom = (float*)(ws + o_denom);
    float* ynum  = (float*)(ws + o_ynum);
    float* Wc    = (float*)(ws + o_wc);
    float* bc    = (float*)(ws + o_bc);
    float* wsT   = (float*)(ws + o_wsT);
    float* wdT   = (float*)(ws + o_wdT);
    float* wso   = (float*)(ws + o_wso);
    float* cy    = (float*)(ws + o_cy);
    bf16*  whhb  = (bf16*)(ws + o_whhb);

    prep_kernel<<<515, 256, 0, stream>>>(pre_w, pre_b, w_ih, b_ih, b_hh, w_hh, wsrc, wdst,
                                         outw, outb, gatb, Wc, bc, wsT, wdT, wso, cy, whhb);
    xw_kernel<<<2048, 512, 0, stream>>>(input, Wc, bc, xw);
    lstm_kernel<<<8, 256, 0, stream>>>(xw, whhb, hidden, cell, outs, dout);
    fsfd_kernel<<<1024, 256, 0, stream>>>(outs, wsT, wdT, fs, fd);
    fso_kernel<<<8192, 256, 0, stream>>>(outs, wso, fso);
    hipMemsetAsync(ws + o_denom, 0, 262144, stream);   // denom + ynum
    edge_kernel<<<(nE + 3) / 4, 256, 0, stream>>>(esrc, edst, fs, fd, attn, fso,
                                                  denom, ynum, nE);
    final_kernel<<<128, 256, 0, stream>>>(ynum, denom, cy, dout);
}